// Round 9
// baseline (88.660 us; speedup 1.0000x reference)
//
#include <hip/hip_runtime.h>
#include <hip/hip_bf16.h>
#include <math.h>

#define NUM_CLASSES 10
#define BATCH 2048
#define DIM 128
#define INV_T 14.285714285714286f   // 1/0.07; TEMPERATURE/BASE_TEMPERATURE = 1
#define NTILE 16                    // 2048/128 row stripes
#define NPAIR 136                   // upper-triangular 128x128 block pairs

typedef __attribute__((ext_vector_type(8))) short bf16x8;   // 8 bf16 = 4 VGPRs
typedef __attribute__((ext_vector_type(4))) float f32x4;    // MFMA accumulator

// Async 16B-per-lane global->LDS. LDS dest = wave-uniform base + lane*16.
__device__ __forceinline__ void load_lds16(const void* g, void* lds) {
    __builtin_amdgcn_global_load_lds(
        (const __attribute__((address_space(1))) unsigned int*)g,
        (__attribute__((address_space(3))) unsigned int*)lds,
        16, 0, 0);
}

// ---------------------------------------------------------------------------
// 1) Row-normalize preds -> bf16 g; fuse zeroing of denom/s2 accumulators;
//    block 0 initializes out[0] = sum(log_vars) (final_kernel atomicAdds).
// ---------------------------------------------------------------------------
__global__ __launch_bounds__(256) void normalize_kernel(
    const float* __restrict__ preds, __hip_bfloat16* __restrict__ g,
    float* __restrict__ zero_buf, const float* __restrict__ log_vars,
    float* __restrict__ out)
{
    int b = blockIdx.x;
    int t = threadIdx.x;
    if (t < 8) zero_buf[b * 8 + t] = 0.0f;   // 5120*8 = 40960 floats (denom+s2)
    if (b == 0 && t == 0) {
        float lv = 0.0f;
        for (int i = 0; i < NUM_CLASSES; ++i) lv += log_vars[i];
        out[0] = lv;
    }

    int row  = b * 4 + (t >> 6);
    int lane = t & 63;
    const float2* src = (const float2*)(preds + (size_t)row * DIM);
    float2 v = src[lane];
    float ss = v.x * v.x + v.y * v.y;
#pragma unroll
    for (int m = 32; m; m >>= 1) ss += __shfl_xor(ss, m, 64);
    float rn = 1.0f / sqrtf(ss);
    __hip_bfloat162 o;
    o.x = __float2bfloat16(v.x * rn);
    o.y = __float2bfloat16(v.y * rn);
    *(__hip_bfloat162*)(g + (size_t)row * DIM + lane * 2) = o;
}

// ---------------------------------------------------------------------------
// 2) MFMA Gram, upper-tri blocks only. K staged in TWO 64-wide halves into
//    a 32 KiB LDS footprint (5 blocks/CU vs 2 at 64 KiB). Async
//    global_load_lds, XOR swizzle pos = chunk ^ (row&7), row stride 64.
//    Epilogue pre-reduces (tx, tx+8) pairs so transpose buffers fit 32 KiB:
//    rbuf 18432 B + cbuf 10240 B = 28672 B.
// ---------------------------------------------------------------------------
__global__ __launch_bounds__(256) void gram_kernel(
    const __hip_bfloat16* __restrict__ g, const int* __restrict__ target,
    float* __restrict__ denom, float* __restrict__ s2)
{
    // decode upper-tri pair (by <= bx)
    int p = blockIdx.x;
    int by = 0, rem = NTILE;
    while (p >= rem) { p -= rem; --rem; ++by; }
    const int bx   = by + p;
    const int cls  = blockIdx.y;
    const int row0 = by * 128;
    const int col0 = bx * 128;
    const bool isDiag = (by == bx);
    const ushort* gc = (const ushort*)g + (size_t)cls * BATCH * DIM;

    __shared__ __align__(16) ushort smem[2 * 128 * 64];   // 32768 B
    ushort* As = smem;                 // 128 rows x 64 (one K-half)
    ushort* Bs = smem + 128 * 64;

    const int t    = threadIdx.x;
    const int wid  = t >> 6;
    const int lane = t & 63;
    const int tx   = lane & 15;        // C/D: col = lane&15; frag row sel
    const int quad = lane >> 4;        // C/D: row = quad*4 + reg
    const int wm   = (wid >> 1) * 64;
    const int wn   = (wid & 1) * 64;

    const int lr = lane >> 3;          // row-within-8 (staging)
    const int lp = lane & 7;           // chunk position 0..7

    f32x4 acc[4][4] = {};

    for (int h = 0; h < 2; ++h) {
        // ---- stage one K-half: 4 (+4) global_load_lds_dwordx4 per wave ----
#pragma unroll
        for (int s = 0; s < 4; ++s) {
            int rb = (s * 4 + wid) * 8;          // wave-uniform row base
            int r  = rb + lr;
            int c  = lp ^ (r & 7);               // fetch chunk c into pos lp
            const ushort* srcA = gc + (size_t)(row0 + r) * DIM + h * 64 + c * 8;
            load_lds16(srcA, &As[rb * 64]);
            if (!isDiag) {
                const ushort* srcB = gc + (size_t)(col0 + r) * DIM + h * 64 + c * 8;
                load_lds16(srcB, &Bs[rb * 64]);
            }
        }
        __syncthreads();   // drains vmcnt before LDS reads

        const ushort* BsR = isDiag ? As : Bs;
#pragma unroll
        for (int lk = 0; lk < 2; ++lk) {
            bf16x8 af[4], bg[4];
#pragma unroll
            for (int i = 0; i < 4; ++i) {
                int pa = ((lk * 4 + quad) ^ (tx & 7)) * 8;   // swizzled chunk
                af[i] = *(const bf16x8*)&As [(wm + i * 16 + tx) * 64 + pa];
                bg[i] = *(const bf16x8*)&BsR[(wn + i * 16 + tx) * 64 + pa];
            }
#pragma unroll
            for (int i = 0; i < 4; ++i)
#pragma unroll
                for (int j = 0; j < 4; ++j)
                    acc[i][j] = __builtin_amdgcn_mfma_f32_16x16x32_bf16(
                        af[i], bg[j], acc[i][j], 0, 0, 0);
        }
        __syncthreads();   // half's LDS reads done; safe to restage / reuse
    }

    // ---- epilogue: register partials -> LDS transpose -> atomics ----
    unsigned laMask = 0;
#pragma unroll
    for (int i = 0; i < 4; ++i)
#pragma unroll
        for (int r = 0; r < 4; ++r)
            if (target[row0 + wm + i * 16 + quad * 4 + r] == cls)
                laMask |= 1u << (i * 4 + r);
    int lb[4];
#pragma unroll
    for (int j = 0; j < 4; ++j) lb[j] = (target[col0 + wn + j * 16 + tx] == cls);

    float2* rbuf = (float2*)smem;              // [wid][64 rows x9][tx<8] 18432 B
    float2* cbuf = (float2*)smem + 4 * 576;    // [wid][64 cols x5][quad] 10240 B
    float2 pcol[4] = {};

#pragma unroll
    for (int i = 0; i < 4; ++i) {
        float2 prow[4] = {};
#pragma unroll
        for (int j = 0; j < 4; ++j) {
            int cg = col0 + wn + j * 16 + tx;
            int lbj = lb[j];
#pragma unroll
            for (int r = 0; r < 4; ++r) {
                int rg = row0 + wm + i * 16 + quad * 4 + r;
                float logit = acc[i][j][r] * INV_T;
                float e = __expf(logit);
                bool dg = isDiag && (cg == rg);
                e = dg ? 0.0f : e;
                bool same = (((laMask >> (i * 4 + r)) & 1) == (unsigned)lbj) && !dg;
                float sl = same ? logit : 0.0f;
                prow[r].x += e; prow[r].y += sl;
                pcol[j].x += e; pcol[j].y += sl;
            }
        }
        // pair-reduce (tx, tx+8), then lanes tx<8 hold the pair sum
#pragma unroll
        for (int r = 0; r < 4; ++r) {
            prow[r].x += __shfl_xor(prow[r].x, 8, 64);
            prow[r].y += __shfl_xor(prow[r].y, 8, 64);
            if (tx < 8)
                rbuf[wid * 576 + (i * 16 + quad * 4 + r) * 9 + tx] = prow[r];
        }
    }
#pragma unroll
    for (int j = 0; j < 4; ++j)
        cbuf[wid * 320 + (j * 16 + tx) * 5 + quad] = pcol[j];
    __syncthreads();

    if (t < 128) {
        // rows: wids 2*grp, 2*grp+1 share wm = 64*grp
        int rl = t & 63, grp = t >> 6;
        float den = 0.0f, sp = 0.0f;
#pragma unroll
        for (int w = 0; w < 2; ++w) {
            int base = (2 * grp + w) * 576 + rl * 9;
#pragma unroll
            for (int x = 0; x < 8; ++x) {
                float2 v = rbuf[base + x];
                den += v.x; sp += v.y;
            }
        }
        atomicAdd(&denom[cls * BATCH + row0 + t], den);
        atomicAdd(&s2   [cls * BATCH + row0 + t], sp);
    } else if (!isDiag) {
        // cols: wids grp, grp+2 share wn = 64*grp
        int u = t - 128;
        int cl = u & 63, grp = u >> 6;
        float den = 0.0f, sp = 0.0f;
#pragma unroll
        for (int w = 0; w < 2; ++w) {
            int base = (grp + 2 * w) * 320 + cl * 5;
#pragma unroll
            for (int q = 0; q < 4; ++q) {
                float2 v = cbuf[base + q];
                den += v.x; sp += v.y;
            }
        }
        atomicAdd(&denom[cls * BATCH + col0 + u], den);
        atomicAdd(&s2   [cls * BATCH + col0 + u], sp);
    }
}

// ---------------------------------------------------------------------------
// 3) Finalize, parallel: 80 blocks x 256 threads, one thread per (cls,row).
// ---------------------------------------------------------------------------
__global__ __launch_bounds__(256) void final_kernel(
    const float* __restrict__ denom, const float* __restrict__ s2,
    const int* __restrict__ target, const float* __restrict__ log_vars,
    float* __restrict__ out)
{
    __shared__ int cw[4];
    __shared__ float wred[4];
    const int t   = threadIdx.x;
    const int idx = blockIdx.x * 256 + t;
    const int cls = idx >> 11;            // block-uniform (2048 % 256 == 0)
    const int a   = idx & (BATCH - 1);

    // block-wide count of (target == cls)
    int c = 0;
#pragma unroll
    for (int k = 0; k < 8; ++k) c += (target[t * 8 + k] == cls);
#pragma unroll
    for (int m = 1; m < 64; m <<= 1) c += __shfl_xor(c, m, 64);
    if ((t & 63) == 0) cw[t >> 6] = c;
    __syncthreads();
    const int c1 = cw[0] + cw[1] + cw[2] + cw[3];

    const int la  = (target[a] == cls);
    const int cnt = la ? (c1 - 1) : (BATCH - c1 - 1);
    float mlpp = s2[idx] / (float)cnt - logf(denom[idx]);
    float part = __expf(-log_vars[cls]) * mlpp;
#pragma unroll
    for (int m = 32; m; m >>= 1) part += __shfl_xor(part, m, 64);
    if ((t & 63) == 0) wred[t >> 6] = part;
    __syncthreads();
    if (t == 0)
        atomicAdd(out, -(wred[0] + wred[1] + wred[2] + wred[3]) / (float)BATCH);
}

// ---------------------------------------------------------------------------
extern "C" void kernel_launch(void* const* d_in, const int* in_sizes, int n_in,
                              void* d_out, int out_size, void* d_ws, size_t ws_size,
                              hipStream_t stream)
{
    const float* preds    = (const float*)d_in[0];   // [10,2048,128] f32
    const int*   target   = (const int*)  d_in[1];   // [2048]
    const float* log_vars = (const float*)d_in[2];   // [10]
    float* out = (float*)d_out;

    __hip_bfloat16* gbf = (__hip_bfloat16*)d_ws;              // 10*2048*128 bf16
    float* denom = (float*)((char*)d_ws + (size_t)NUM_CLASSES * BATCH * DIM * 2);
    float* s2    = denom + (size_t)NUM_CLASSES * BATCH;

    normalize_kernel<<<NUM_CLASSES * BATCH / 4, 256, 0, stream>>>(
        preds, gbf, denom, log_vars, out);
    gram_kernel<<<dim3(NPAIR, NUM_CLASSES), 256, 0, stream>>>(gbf, target, denom, s2);
    final_kernel<<<NUM_CLASSES * BATCH / 256, 256, 0, stream>>>(
        denom, s2, target, log_vars, out);
}